// Round 12
// baseline (68.651 us; speedup 1.0000x reference)
//
#include <hip/hip_runtime.h>
#include <hip/hip_bf16.h>

#define BATCH 8
#define V 2048
#define H 256
#define D 128

typedef __attribute__((ext_vector_type(8))) _Float16 f16x8;
typedef __attribute__((ext_vector_type(4))) float f32x4;
typedef unsigned int uint32;

static __device__ __forceinline__ uint32 pk2(float lo, float hi) {
  __fp16 __attribute__((ext_vector_type(2))) h = __builtin_amdgcn_cvt_pkrtz(lo, hi);
  uint32 u;
  __builtin_memcpy(&u, &h, 4);
  return u;
}

// -------- K_pack: adj -> bitmask words TRANSPOSED [jw][i]; vL/vR = W^T a; Wh = f16(W) --------
__global__ __launch_bounds__(256) void k_pack(const int* __restrict__ adj,
                                              const float* __restrict__ W,
                                              const float* __restrict__ a,
                                              unsigned int* __restrict__ pkT,
                                              float* __restrict__ vL,
                                              float* __restrict__ vR,
                                              _Float16* __restrict__ Wh) {
  const int blk = blockIdx.x;
  if (blk < V) {
    const int w = threadIdx.x >> 6, lane = threadIdx.x & 63;
    const int* row = adj + (size_t)blk * V;
#pragma unroll
    for (int it = 0; it < 8; ++it) {
      const int j = it * 256 + w * 64 + lane;
      unsigned long long m = __ballot(row[j] != 0);
      if (lane < 2) {
        const int jw = it * 8 + w * 2 + lane;
        pkT[(size_t)jw * V + blk] = (unsigned int)(m >> (lane * 32));
      }
    }
  } else if (blk == V) {
    const int h = threadIdx.x;  // 0..255
    float sL = 0.f, sR = 0.f;
    for (int d = 0; d < D; ++d) {
      const float wv = W[(size_t)d * H + h];
      sL += wv * a[d];
      sR += wv * a[D + d];
    }
    vL[h] = sL;
    vR[h] = sR;
  } else {
    const int t = threadIdx.x;
    for (int i = 0; i < D; ++i)
      Wh[(size_t)i * H + t] = (_Float16)W[(size_t)i * H + t];
  }
}

// -------- K_proj: phase0 stage x->f16 LDS + e_i/e_j; phase1 f16 MFMA GEMM;
//          transpose via st; fragment store to pTf --------
__global__ __launch_bounds__(256, 2) void k_proj(const float* __restrict__ x,
                                                 const _Float16* __restrict__ Wh,
                                                 const float* __restrict__ vL,
                                                 const float* __restrict__ vR,
                                                 _Float16* __restrict__ pTf,
                                                 float* __restrict__ ei,
                                                 _Float16* __restrict__ Fh,
                                                 _Float16* __restrict__ Ph) {
  __shared__ char xls[32 * 512];      // 16 KB: 32 j-rows x 256 h f16, XOR-swizzled
  __shared__ _Float16 st[128][52];    // 13 KB transpose staging
  const int t = threadIdx.x, lane = t & 63, wave = t >> 6;
  const int b = blockIdx.x >> 6;
  const int jt0 = blockIdx.x & 63;
  const int j0 = jt0 * 32;
  const int kq = lane >> 4, l15 = lane & 15;

  // ---- phase 0: stage 8 rows per wave; fp32 e-dots fused ----
  {
    const float4 vl4 = *(const float4*)(vL + lane * 4);
    const float4 vr4 = *(const float4*)(vR + lane * 4);
#pragma unroll
    for (int rr = 0; rr < 8; ++rr) {
      const int row = wave * 8 + rr;
      const float4 xv = *(const float4*)(x + ((size_t)(b * V + j0 + row)) * H + lane * 4);
      // f16 convert + swizzled LDS store
      uint32 u0 = pk2(xv.x, xv.y), u1 = pk2(xv.z, xv.w);
      const int off = row * 512 + ((lane * 8) ^ ((row & 7) << 4));
      *(uint32*)(xls + off) = u0;
      *(uint32*)(xls + off + 4) = u1;
      // e dots (fp32)
      float eL = xv.x * vl4.x + xv.y * vl4.y + xv.z * vl4.z + xv.w * vl4.w;
      float eR = xv.x * vr4.x + xv.y * vr4.y + xv.z * vr4.z + xv.w * vr4.w;
#pragma unroll
      for (int off_ = 1; off_ < 64; off_ <<= 1) {
        eL += __shfl_xor(eL, off_, 64);
        eR += __shfl_xor(eR, off_, 64);
      }
      if (lane == 0) {
        const size_t r_ = (size_t)b * V + j0 + row;
        ei[r_] = eL;
        Fh[r_] = (_Float16)__expf(eR);
        Ph[r_] = (_Float16)__expf(0.2f * eR);
      }
    }
  }
  __syncthreads();

  // ---- phase 1: GEMM. wave owns d rows [wave*32, wave*32+32) ----
  f32x4 acc[2][2];  // [t_(dt pair)][jt]
#pragma unroll
  for (int i_ = 0; i_ < 2; ++i_)
#pragma unroll
    for (int j_ = 0; j_ < 2; ++j_) acc[i_][j_] = (f32x4){0.f, 0.f, 0.f, 0.f};

  const char* wbase = (const char*)Wh + ((size_t)(wave * 32 + l15) * H + kq * 8) * 2;
#pragma unroll
  for (int ks = 0; ks < 8; ++ks) {
    f16x8 aw[2], bx[2];
#pragma unroll
    for (int t_ = 0; t_ < 2; ++t_)
      aw[t_] = *(const f16x8*)(wbase + (t_ * 16 * H + ks * 32) * 2);
#pragma unroll
    for (int jt = 0; jt < 2; ++jt) {
      const int row = jt * 16 + l15;
      bx[jt] = *(const f16x8*)(xls + row * 512 + ((ks * 64 + kq * 16) ^ ((l15 & 7) << 4)));
    }
#pragma unroll
    for (int t_ = 0; t_ < 2; ++t_)
#pragma unroll
      for (int jt = 0; jt < 2; ++jt)
        acc[t_][jt] = __builtin_amdgcn_mfma_f32_16x16x32_f16(aw[t_], bx[jt], acc[t_][jt], 0, 0, 0);
  }

  // C regs -> st[d][j]
#pragma unroll
  for (int t_ = 0; t_ < 2; ++t_)
#pragma unroll
    for (int jt = 0; jt < 2; ++jt)
#pragma unroll
      for (int r = 0; r < 4; ++r)
        st[(wave * 2 + t_) * 16 + kq * 4 + r][jt * 16 + l15] = (_Float16)acc[t_][jt][r];
  __syncthreads();

  // fragment store: pTf[b][c][dt][ks][lane][16B]
  const int c = jt0 >> 1;
  const int ksh = jt0 & 1;
  const int g = t >> 6;
#pragma unroll
  for (int ff = 0; ff < 2; ++ff) {
    const int dt = ff * 4 + g;
    const int dR = dt * 16 + l15;
    const int jc = kq * 8;
    union { unsigned long long ll[2]; f16x8 v; } vv_;
    vv_.ll[0] = *(const unsigned long long*)&st[dR][jc];
    vv_.ll[1] = *(const unsigned long long*)&st[dR][jc + 4];
    *(f16x8*)((char*)pTf +
              (((((size_t)b * 32 + c) * 8 + dt) * 2 + ksh) * 64 + lane) * 16) = vv_.v;
  }
}

// -------- K_attn: grid 1024, wave = 32 i x 16 d; JIT WGEN; chain-split accs --------
typedef union { uint4 v; uint32 u[4]; } U4;
typedef union { uint32 u[4]; f16x8 v; } AFu;
struct PFS {
  U4 FH0, FH1, PH0, PH1;  // F/P tables for the chunk
  uint32 w[2][2];         // adj words [ig][ks]
};

#define PKMUL(d, a, b) asm("v_pk_mul_f16 %0, %1, %2" : "=v"(d) : "v"(a), "v"(b));
#define PKMAX(d, a, b) asm("v_pk_max_f16 %0, %1, %2" : "=v"(d) : "v"(a), "v"(b));

#define WGENX(S, AF_)                                                  \
  _Pragma("unroll") for (int ig_ = 0; ig_ < 2; ++ig_) {                \
    const uint32 E2_ = Ei2g[ig_], EP2_ = Eip2g[ig_];                   \
    _Pragma("unroll") for (int ks_ = 0; ks_ < 2; ++ks_) {              \
      U4 M_;                                                           \
      M_.v = lut[(((S).w[ig_][ks_]) >> kq8) & 0xFF];                   \
      const U4& FH_ = ks_ ? (S).FH1 : (S).FH0;                         \
      const U4& PH_ = ks_ ? (S).PH1 : (S).PH0;                         \
      _Pragma("unroll") for (int p_ = 0; p_ < 4; ++p_) {               \
        uint32 t0_, t1_;                                               \
        PKMUL(t0_, E2_, FH_.u[p_])                                     \
        PKMUL(t1_, EP2_, PH_.u[p_])                                    \
        PKMAX(t0_, t0_, t1_)                                           \
        AF_[ig_][ks_].u[p_] = t0_ & M_.u[p_];                          \
      }                                                                \
    }                                                                  \
  }

#define PFETCH(S, C)                                           \
  {                                                            \
    const char* f_ = fbase + (C) * 128 + kq16;                 \
    const char* p_ = pbase + (C) * 128 + kq16;                 \
    (S).FH0.v = *(const uint4*)(f_);                           \
    (S).FH1.v = *(const uint4*)(f_ + 64);                      \
    (S).PH0.v = *(const uint4*)(p_);                           \
    (S).PH1.v = *(const uint4*)(p_ + 64);                      \
    (S).w[0][0] = adjpT[(size_t)((C) * 2) * V + iR0];          \
    (S).w[0][1] = adjpT[(size_t)((C) * 2 + 1) * V + iR0];      \
    (S).w[1][0] = adjpT[(size_t)((C) * 2) * V + iR1];          \
    (S).w[1][1] = adjpT[(size_t)((C) * 2 + 1) * V + iR1];      \
  }

#define LOADB(BR, C)                                  \
  {                                                   \
    const char* g_ = gbase + (size_t)(C) * 16384;     \
    BR[0] = *(const f16x8*)(g_);                      \
    BR[1] = *(const f16x8*)(g_ + 1024);               \
  }

#define DOMFMA(AF_, BX)                                                        \
  _Pragma("unroll") for (int ig_ = 0; ig_ < 2; ++ig_)                          \
    _Pragma("unroll") for (int ks_ = 0; ks_ < 2; ++ks_) {                      \
      acc[ig_][ks_] = __builtin_amdgcn_mfma_f32_16x16x32_f16(                  \
          AF_[ig_][ks_].v, BX[ks_], acc[ig_][ks_], 0, 0, 0);                   \
      accS[ig_][ks_] = __builtin_amdgcn_mfma_f32_16x16x32_f16(                 \
          AF_[ig_][ks_].v, onesv, accS[ig_][ks_], 0, 0, 0);                    \
    }

#define BODYF(C, S, BX)       \
  {                           \
    AFu af_[2][2];            \
    WGENX(S, af_)             \
    DOMFMA(af_, BX)           \
    LOADB(BX, (C) + 2)        \
    PFETCH(S, (C) + 2)        \
  }

#define BODYT(S, BX)          \
  {                           \
    AFu af_[2][2];            \
    WGENX(S, af_)             \
    DOMFMA(af_, BX)           \
  }

__global__ __launch_bounds__(256, 4) void k_attn(
    const _Float16* __restrict__ pTf,
    const float* __restrict__ ei,
    const _Float16* __restrict__ Fht,
    const _Float16* __restrict__ Pht,
    const unsigned int* __restrict__ adjpT,
    float* __restrict__ out) {
  __shared__ uint4 lut[256];  // adj-byte -> f16x2 mask words
  {
    const int tb = threadIdx.x;
    const uint32 m0 = ((tb & 1) ? 0xFFFFu : 0u) | ((tb & 2) ? 0xFFFF0000u : 0u);
    const uint32 m1 = ((tb & 4) ? 0xFFFFu : 0u) | ((tb & 8) ? 0xFFFF0000u : 0u);
    const uint32 m2 = ((tb & 16) ? 0xFFFFu : 0u) | ((tb & 32) ? 0xFFFF0000u : 0u);
    const uint32 m3 = ((tb & 64) ? 0xFFFFu : 0u) | ((tb & 128) ? 0xFFFF0000u : 0u);
    lut[tb] = make_uint4(m0, m1, m2, m3);
  }
  __syncthreads();  // write-once LUT; read-only afterwards

  const int t = threadIdx.x, lane = t & 63;
  const int dq = t >> 6;  // wave = d-slice 0..3
  // bijective XCD chunk swizzle (nwg=1024, 128 per XCD)
  const int pay = (blockIdx.x & 7) * 128 + (blockIdx.x >> 3);
  const int b = pay >> 7;
  const int dh = (pay >> 6) & 1;
  const int it = pay & 63;
  const int i0 = it * 32;
  const int kq = lane >> 4;
  const int kq8 = kq * 8;
  const int kq16 = kq * 16;
  const int l15 = lane & 15;
  const int iR0 = i0 + l15;
  const int iR1 = iR0 + 16;

  const float eiv0 = ei[(size_t)b * V + iR0];
  const float eiv1 = ei[(size_t)b * V + iR1];
  uint32 Ei2g[2], Eip2g[2];
  {
    const float e0 = __expf(eiv0), e1 = __expf(eiv1);
    const float p0 = __expf(0.2f * eiv0), p1 = __expf(0.2f * eiv1);
    Ei2g[0] = pk2(e0, e0); Ei2g[1] = pk2(e1, e1);
    Eip2g[0] = pk2(p0, p0); Eip2g[1] = pk2(p1, p1);
  }
  const char* fbase = (const char*)(Fht + (size_t)b * V);
  const char* pbase = (const char*)(Pht + (size_t)b * V);
  const char* gbase = (const char*)pTf + ((size_t)b * 32) * 16384 +
                      (size_t)(dh * 4 + dq) * 2048 + lane * 16;

  union { uint32 u[4]; f16x8 v; } ones_;
  ones_.u[0] = ones_.u[1] = ones_.u[2] = ones_.u[3] = 0x3C003C00u;
  const f16x8 onesv = ones_.v;

  f32x4 acc[2][2];   // [ig][ks]
  f32x4 accS[2][2];  // [ig][ks] rowsums via ones-MFMA
#pragma unroll
  for (int a_ = 0; a_ < 2; ++a_)
#pragma unroll
    for (int c_ = 0; c_ < 2; ++c_) {
      acc[a_][c_] = (f32x4){0.f, 0.f, 0.f, 0.f};
      accS[a_][c_] = (f32x4){0.f, 0.f, 0.f, 0.f};
    }

  f16x8 bA[2], bB[2];
  PFS sA, sB;

  // prologue
  LOADB(bA, 0)
  LOADB(bB, 1)
  PFETCH(sA, 0)
  PFETCH(sB, 1)

  for (int c2 = 0; c2 < 15; ++c2) {
    const int c = c2 * 2;
    BODYF(c, sA, bA)
    BODYF(c + 1, sB, bB)
  }
  // tail: chunks 30, 31 (no further loads)
  BODYT(sA, bA)
  BODYT(sB, bB)

  // epilogue: denominators in accS (lane-aligned), scale + relu + store
  float* ob = out + ((size_t)b * V + i0) * D + dh * 64 + dq * 16 + l15;
#pragma unroll
  for (int ig = 0; ig < 2; ++ig) {
#pragma unroll
    for (int r = 0; r < 4; ++r) {
      const float inv_ = 1.0f / (accS[ig][0][r] + accS[ig][1][r]);
      const float v = (acc[ig][0][r] + acc[ig][1][r]) * inv_;
      ob[(size_t)(ig * 16 + kq * 4 + r) * D] = fmaxf(v, 0.f);
    }
  }
}

extern "C" void kernel_launch(void* const* d_in, const int* in_sizes, int n_in,
                              void* d_out, int out_size, void* d_ws, size_t ws_size,
                              hipStream_t stream) {
  const float* x = (const float*)d_in[0];
  const int* adj = (const int*)d_in[1];
  const float* W = (const float*)d_in[2];
  const float* a = (const float*)d_in[3];
  float* out = (float*)d_out;

  char* ws = (char*)d_ws;
  _Float16* pTf = (_Float16*)ws;                                   // 4 MB
  float* ei = (float*)(ws + (4u << 20));                           // 64 KB
  _Float16* Fh = (_Float16*)(ws + (4u << 20) + 65536);             // 32 KB
  _Float16* Ph = (_Float16*)(ws + (4u << 20) + 98304);             // 32 KB
  unsigned int* adjpT = (unsigned int*)(ws + (4u << 20) + 131072); // 512 KB
  float* vL = (float*)(ws + (4u << 20) + 655360);                  // 1 KB
  float* vR = (float*)(ws + (4u << 20) + 656384);                  // 1 KB
  _Float16* Wh = (_Float16*)(ws + (4u << 20) + 657408);            // 64 KB

  k_pack<<<dim3(V + 2), dim3(256), 0, stream>>>(adj, W, a, adjpT, vL, vR, Wh);
  k_proj<<<dim3(BATCH * (V / 32)), dim3(256), 0, stream>>>(x, Wh, vL, vR, pTf, ei, Fh, Ph);
  k_attn<<<dim3(BATCH * 2 * (V / 32)), dim3(256), 0, stream>>>(pTf, ei, Fh, Ph, adjpT, out);
}

// Round 13
// 54.476 us; speedup vs baseline: 1.2602x; 1.2602x over previous
//
#include <hip/hip_runtime.h>
#include <hip/hip_bf16.h>

#define BATCH 8
#define V 2048
#define H 256
#define D 128

typedef __attribute__((ext_vector_type(8))) _Float16 f16x8;
typedef __attribute__((ext_vector_type(4))) float f32x4;
typedef unsigned int uint32;

static __device__ __forceinline__ uint32 pk2(float lo, float hi) {
  __fp16 __attribute__((ext_vector_type(2))) h = __builtin_amdgcn_cvt_pkrtz(lo, hi);
  uint32 u;
  __builtin_memcpy(&u, &h, 4);
  return u;
}

// -------- K_pack: adj -> bitmask words TRANSPOSED [jw][i]; vL/vR = W^T a; Wh = f16(W) --------
__global__ __launch_bounds__(256) void k_pack(const int* __restrict__ adj,
                                              const float* __restrict__ W,
                                              const float* __restrict__ a,
                                              unsigned int* __restrict__ pkT,
                                              float* __restrict__ vL,
                                              float* __restrict__ vR,
                                              _Float16* __restrict__ Wh) {
  const int blk = blockIdx.x;
  if (blk < V) {
    const int w = threadIdx.x >> 6, lane = threadIdx.x & 63;
    const int* row = adj + (size_t)blk * V;
#pragma unroll
    for (int it = 0; it < 8; ++it) {
      const int j = it * 256 + w * 64 + lane;
      unsigned long long m = __ballot(row[j] != 0);
      if (lane < 2) {
        const int jw = it * 8 + w * 2 + lane;
        pkT[(size_t)jw * V + blk] = (unsigned int)(m >> (lane * 32));
      }
    }
  } else if (blk == V) {
    const int h = threadIdx.x;  // 0..255
    float sL = 0.f, sR = 0.f;
    for (int d = 0; d < D; ++d) {
      const float wv = W[(size_t)d * H + h];
      sL += wv * a[d];
      sR += wv * a[D + d];
    }
    vL[h] = sL;
    vR[h] = sR;
  } else {
    const int t = threadIdx.x;
    for (int i = 0; i < D; ++i)
      Wh[(size_t)i * H + t] = (_Float16)W[(size_t)i * H + t];
  }
}

// -------- K_proj: phase0 stage x->f16 LDS + e_i/e_j; phase1 f16 MFMA GEMM;
//          transpose via st; fragment store to pTf (R12, verified) --------
__global__ __launch_bounds__(256, 2) void k_proj(const float* __restrict__ x,
                                                 const _Float16* __restrict__ Wh,
                                                 const float* __restrict__ vL,
                                                 const float* __restrict__ vR,
                                                 _Float16* __restrict__ pTf,
                                                 float* __restrict__ ei,
                                                 _Float16* __restrict__ Fh,
                                                 _Float16* __restrict__ Ph) {
  __shared__ char xls[32 * 512];      // 16 KB: 32 j-rows x 256 h f16, XOR-swizzled
  __shared__ _Float16 st[128][52];    // 13 KB transpose staging
  const int t = threadIdx.x, lane = t & 63, wave = t >> 6;
  const int b = blockIdx.x >> 6;
  const int jt0 = blockIdx.x & 63;
  const int j0 = jt0 * 32;
  const int kq = lane >> 4, l15 = lane & 15;

  // ---- phase 0: stage 8 rows per wave; fp32 e-dots fused ----
  {
    const float4 vl4 = *(const float4*)(vL + lane * 4);
    const float4 vr4 = *(const float4*)(vR + lane * 4);
#pragma unroll
    for (int rr = 0; rr < 8; ++rr) {
      const int row = wave * 8 + rr;
      const float4 xv = *(const float4*)(x + ((size_t)(b * V + j0 + row)) * H + lane * 4);
      uint32 u0 = pk2(xv.x, xv.y), u1 = pk2(xv.z, xv.w);
      const int off = row * 512 + ((lane * 8) ^ ((row & 7) << 4));
      *(uint32*)(xls + off) = u0;
      *(uint32*)(xls + off + 4) = u1;
      float eL = xv.x * vl4.x + xv.y * vl4.y + xv.z * vl4.z + xv.w * vl4.w;
      float eR = xv.x * vr4.x + xv.y * vr4.y + xv.z * vr4.z + xv.w * vr4.w;
#pragma unroll
      for (int off_ = 1; off_ < 64; off_ <<= 1) {
        eL += __shfl_xor(eL, off_, 64);
        eR += __shfl_xor(eR, off_, 64);
      }
      if (lane == 0) {
        const size_t r_ = (size_t)b * V + j0 + row;
        ei[r_] = eL;
        Fh[r_] = (_Float16)__expf(eR);
        Ph[r_] = (_Float16)__expf(0.2f * eR);
      }
    }
  }
  __syncthreads();

  // ---- phase 1: GEMM. wave owns d rows [wave*32, wave*32+32) ----
  f32x4 acc[2][2];  // [t_(dt pair)][jt]
#pragma unroll
  for (int i_ = 0; i_ < 2; ++i_)
#pragma unroll
    for (int j_ = 0; j_ < 2; ++j_) acc[i_][j_] = (f32x4){0.f, 0.f, 0.f, 0.f};

  const char* wbase = (const char*)Wh + ((size_t)(wave * 32 + l15) * H + kq * 8) * 2;
#pragma unroll
  for (int ks = 0; ks < 8; ++ks) {
    f16x8 aw[2], bx[2];
#pragma unroll
    for (int t_ = 0; t_ < 2; ++t_)
      aw[t_] = *(const f16x8*)(wbase + (t_ * 16 * H + ks * 32) * 2);
#pragma unroll
    for (int jt = 0; jt < 2; ++jt) {
      const int row = jt * 16 + l15;
      bx[jt] = *(const f16x8*)(xls + row * 512 + ((ks * 64 + kq * 16) ^ ((l15 & 7) << 4)));
    }
#pragma unroll
    for (int t_ = 0; t_ < 2; ++t_)
#pragma unroll
      for (int jt = 0; jt < 2; ++jt)
        acc[t_][jt] = __builtin_amdgcn_mfma_f32_16x16x32_f16(aw[t_], bx[jt], acc[t_][jt], 0, 0, 0);
  }

  // C regs -> st[d][j]
#pragma unroll
  for (int t_ = 0; t_ < 2; ++t_)
#pragma unroll
    for (int jt = 0; jt < 2; ++jt)
#pragma unroll
      for (int r = 0; r < 4; ++r)
        st[(wave * 2 + t_) * 16 + kq * 4 + r][jt * 16 + l15] = (_Float16)acc[t_][jt][r];
  __syncthreads();

  // fragment store: pTf[b][c][dt][ks][lane][16B]
  const int c = jt0 >> 1;
  const int ksh = jt0 & 1;
  const int g = t >> 6;
#pragma unroll
  for (int ff = 0; ff < 2; ++ff) {
    const int dt = ff * 4 + g;
    const int dR = dt * 16 + l15;
    const int jc = kq * 8;
    union { unsigned long long ll[2]; f16x8 v; } vv_;
    vv_.ll[0] = *(const unsigned long long*)&st[dR][jc];
    vv_.ll[1] = *(const unsigned long long*)&st[dR][jc + 4];
    *(f16x8*)((char*)pTf +
              (((((size_t)b * 32 + c) * 8 + dt) * 2 + ksh) * 64 + lane) * 16) = vv_.v;
  }
}

// -------- K_attn: R11 geometry (wave = 32i x 32d), register-only mask gen --------
// bit->f16(2.0) via shift/AND into bit14/bit30; 0.5 compensation folded into Ei2/Eip2.
// No LDS, no barriers, chain-split accumulators, ones-column rowsum MFMA.

typedef union { uint4 v; uint32 u[4]; } U4;
typedef union { uint32 u[4]; f16x8 v; } AFu;
struct PFS {
  U4 FH0, FH1, PH0, PH1;  // F/P tables, shared by both i-groups
  uint32 w[2][2];         // adj words [ig][ks]
  AFu AF[2][2];           // A fragments [ig][ks]
};

#define PKMUL(d, a, b) asm("v_pk_mul_f16 %0, %1, %2" : "=v"(d) : "v"(a), "v"(b));
#define PKMAX(d, a, b) asm("v_pk_max_f16 %0, %1, %2" : "=v"(d) : "v"(a), "v"(b));

#define WGEN(S)                                                        \
  _Pragma("unroll") for (int ig_ = 0; ig_ < 2; ++ig_) {                \
    const uint32 E2_ = Ei2g[ig_], EP2_ = Eip2g[ig_];                   \
    _Pragma("unroll") for (int ks_ = 0; ks_ < 2; ++ks_) {              \
      const uint32 sh_ = (S).w[ig_][ks_] >> kq8;                       \
      _Pragma("unroll") for (int p_ = 0; p_ < 4; ++p_) {               \
        uint32 t0_, t1_;                                               \
        PKMUL(t0_, E2_, (ks_ ? (S).FH1 : (S).FH0).u[p_])               \
        PKMUL(t1_, EP2_, (ks_ ? (S).PH1 : (S).PH0).u[p_])              \
        PKMAX(t0_, t0_, t1_)                                           \
        const uint32 m_ = ((sh_ << (14 - 2 * p_)) & 0x4000u) |         \
                          ((sh_ << (29 - 2 * p_)) & 0x40000000u);      \
        PKMUL((S).AF[ig_][ks_].u[p_], t0_, m_)                         \
      }                                                                \
    }                                                                  \
  }

#define PFETCH(S, C)                                       \
  {                                                        \
    const char* f_ = fbase + (C) * 128 + kq16;             \
    const char* p_ = pbase + (C) * 128 + kq16;             \
    (S).FH0.v = *(const uint4*)(f_);                       \
    (S).FH1.v = *(const uint4*)(f_ + 64);                  \
    (S).PH0.v = *(const uint4*)(p_);                       \
    (S).PH1.v = *(const uint4*)(p_ + 64);                  \
    (S).w[0][0] = adjpT[(size_t)((C) * 2) * V + iR0];      \
    (S).w[0][1] = adjpT[(size_t)((C) * 2 + 1) * V + iR0];  \
    (S).w[1][0] = adjpT[(size_t)((C) * 2) * V + iR1];      \
    (S).w[1][1] = adjpT[(size_t)((C) * 2 + 1) * V + iR1];  \
  }

#define LOADB(BR, C)                                      \
  {                                                       \
    const char* g_ = gbase + (size_t)(C) * 16384;         \
    _Pragma("unroll") for (int q_ = 0; q_ < 4; ++q_)      \
      BR[q_] = *(const f16x8*)(g_ + q_ * 1024);           \
  }

#define DOMFMA(S, BX)                                                          \
  _Pragma("unroll") for (int ig_ = 0; ig_ < 2; ++ig_)                          \
    _Pragma("unroll") for (int nt_ = 0; nt_ < 2; ++nt_)                        \
      _Pragma("unroll") for (int ks_ = 0; ks_ < 2; ++ks_)                      \
        acc[ig_][nt_][ks_] = __builtin_amdgcn_mfma_f32_16x16x32_f16(           \
            (S).AF[ig_][ks_].v, BX[nt_ * 2 + ks_], acc[ig_][nt_][ks_], 0, 0, 0); \
  _Pragma("unroll") for (int ig_ = 0; ig_ < 2; ++ig_)                          \
    _Pragma("unroll") for (int ks_ = 0; ks_ < 2; ++ks_)                        \
      accS[ig_][ks_] = __builtin_amdgcn_mfma_f32_16x16x32_f16(                 \
          (S).AF[ig_][ks_].v, onesv, accS[ig_][ks_], 0, 0, 0);

#define BODYF(C, SX, BX, SY)   \
  {                            \
    DOMFMA(SX, BX)             \
    WGEN(SY)                   \
    LOADB(BX, (C) + 2)         \
    PFETCH(SX, (C) + 2)        \
  }

__global__ __launch_bounds__(256, 2) void k_attn(
    const _Float16* __restrict__ pTf,
    const float* __restrict__ ei,
    const _Float16* __restrict__ Fht,
    const _Float16* __restrict__ Pht,
    const unsigned int* __restrict__ adjpT,
    float* __restrict__ out) {
  const int t = threadIdx.x, lane = t & 63, wave = t >> 6;
  const int ih = wave >> 1;  // i-half of block (0/1)
  const int dq = wave & 1;   // d-quarter of dh-half (0/1)
  // bijective XCD chunk swizzle (nwg=512, 64 per XCD)
  const int pay = (blockIdx.x & 7) * 64 + (blockIdx.x >> 3);
  const int bdh = pay >> 4;   // 0..31
  const int itl = pay & 15;
  const int b = bdh >> 2, dh = (bdh >> 1) & 1;
  const int it = ((bdh & 1) << 4) | itl;  // 0..31
  const int i0b = it * 64;
  const int kq = lane >> 4;
  const int kq8 = kq * 8;
  const int kq16 = kq * 16;
  const int l15 = lane & 15;
  const int ibase = i0b + ih * 32;
  const int iR0 = ibase + l15;
  const int iR1 = iR0 + 16;

  const float eiv0 = ei[(size_t)b * V + iR0];
  const float eiv1 = ei[(size_t)b * V + iR1];
  uint32 Ei2g[2], Eip2g[2];
  {
    // 0.5x folded in to compensate the f16 2.0-mask
    const float e0 = 0.5f * __expf(eiv0), e1 = 0.5f * __expf(eiv1);
    const float p0 = 0.5f * __expf(0.2f * eiv0), p1 = 0.5f * __expf(0.2f * eiv1);
    Ei2g[0] = pk2(e0, e0); Ei2g[1] = pk2(e1, e1);
    Eip2g[0] = pk2(p0, p0); Eip2g[1] = pk2(p1, p1);
  }
  const char* fbase = (const char*)(Fht + (size_t)b * V);
  const char* pbase = (const char*)(Pht + (size_t)b * V);
  const size_t fb0 = ((size_t)b * 32) * 16384 + (size_t)dh * 8192;
  const char* gbase = (const char*)pTf + fb0 + dq * 4096 + lane * 16;

  union { uint32 u[4]; f16x8 v; } ones_;
  ones_.u[0] = ones_.u[1] = ones_.u[2] = ones_.u[3] = 0x3C003C00u;
  const f16x8 onesv = ones_.v;

  f32x4 acc[2][2][2];  // [ig][nt][ks]
#pragma unroll
  for (int a_ = 0; a_ < 2; ++a_)
#pragma unroll
    for (int b_ = 0; b_ < 2; ++b_)
#pragma unroll
      for (int c_ = 0; c_ < 2; ++c_) acc[a_][b_][c_] = (f32x4){0.f, 0.f, 0.f, 0.f};
  f32x4 accS[2][2];  // [ig][ks]
#pragma unroll
  for (int a_ = 0; a_ < 2; ++a_)
#pragma unroll
    for (int c_ = 0; c_ < 2; ++c_) accS[a_][c_] = (f32x4){0.f, 0.f, 0.f, 0.f};

  f16x8 bA[4], bB[4];
  PFS sA, sB;

  // prologue
  LOADB(bA, 0)
  LOADB(bB, 1)
  PFETCH(sA, 0)
  PFETCH(sB, 1)
  WGEN(sA)

  for (int c2 = 0; c2 < 15; ++c2) {
    const int c = c2 * 2;
    BODYF(c, sA, bA, sB)
    BODYF(c + 1, sB, bB, sA)
  }
  // tail: chunk 30 (af for 31 built, no more loads), chunk 31
  {
    DOMFMA(sA, bA)
    WGEN(sB)
  }
  { DOMFMA(sB, bB) }

  // epilogue: rowsums in accS (ones-column MFMA), lane-aligned
  float* ob = out + ((size_t)b * V + ibase) * D + dh * 64 + dq * 32 + l15;
#pragma unroll
  for (int ig = 0; ig < 2; ++ig) {
#pragma unroll
    for (int r = 0; r < 4; ++r) {
      const float inv_ = 1.0f / (accS[ig][0][r] + accS[ig][1][r]);
#pragma unroll
      for (int nt = 0; nt < 2; ++nt) {
        const float v = (acc[ig][nt][0][r] + acc[ig][nt][1][r]) * inv_;
        ob[(size_t)(ig * 16 + kq * 4 + r) * D + nt * 16] = fmaxf(v, 0.f);
      }
    }
  }
}

extern "C" void kernel_launch(void* const* d_in, const int* in_sizes, int n_in,
                              void* d_out, int out_size, void* d_ws, size_t ws_size,
                              hipStream_t stream) {
  const float* x = (const float*)d_in[0];
  const int* adj = (const int*)d_in[1];
  const float* W = (const float*)d_in[2];
  const float* a = (const float*)d_in[3];
  float* out = (float*)d_out;

  char* ws = (char*)d_ws;
  _Float16* pTf = (_Float16*)ws;                                   // 4 MB
  float* ei = (float*)(ws + (4u << 20));                           // 64 KB
  _Float16* Fh = (_Float16*)(ws + (4u << 20) + 65536);             // 32 KB
  _Float16* Ph = (_Float16*)(ws + (4u << 20) + 98304);             // 32 KB
  unsigned int* adjpT = (unsigned int*)(ws + (4u << 20) + 131072); // 512 KB
  float* vL = (float*)(ws + (4u << 20) + 655360);                  // 1 KB
  float* vR = (float*)(ws + (4u << 20) + 656384);                  // 1 KB
  _Float16* Wh = (_Float16*)(ws + (4u << 20) + 657408);            // 64 KB

  k_pack<<<dim3(V + 2), dim3(256), 0, stream>>>(adj, W, a, adjpT, vL, vR, Wh);
  k_proj<<<dim3(BATCH * (V / 32)), dim3(256), 0, stream>>>(x, Wh, vL, vR, pTf, ei, Fh, Ph);
  k_attn<<<dim3(BATCH * 2 * (V / 64)), dim3(256), 0, stream>>>(pTf, ei, Fh, Ph, adjpT, out);
}

// Round 14
// 54.441 us; speedup vs baseline: 1.2610x; 1.0006x over previous
//
#include <hip/hip_runtime.h>
#include <hip/hip_bf16.h>

#define BATCH 8
#define V 2048
#define H 256
#define D 128

typedef __attribute__((ext_vector_type(8))) _Float16 f16x8;
typedef __attribute__((ext_vector_type(4))) float f32x4;
typedef unsigned int uint32;

static __device__ __forceinline__ uint32 pk2(float lo, float hi) {
  __fp16 __attribute__((ext_vector_type(2))) h = __builtin_amdgcn_cvt_pkrtz(lo, hi);
  uint32 u;
  __builtin_memcpy(&u, &h, 4);
  return u;
}

// -------- K_pack: adj -> bitmask words TRANSPOSED [jw][i]; vL/vR = W^T a; Wh = f16(W) --------
__global__ __launch_bounds__(256) void k_pack(const int* __restrict__ adj,
                                              const float* __restrict__ W,
                                              const float* __restrict__ a,
                                              unsigned int* __restrict__ pkT,
                                              float* __restrict__ vL,
                                              float* __restrict__ vR,
                                              _Float16* __restrict__ Wh) {
  const int blk = blockIdx.x;
  if (blk < V) {
    const int w = threadIdx.x >> 6, lane = threadIdx.x & 63;
    const int* row = adj + (size_t)blk * V;
#pragma unroll
    for (int it = 0; it < 8; ++it) {
      const int j = it * 256 + w * 64 + lane;
      unsigned long long m = __ballot(row[j] != 0);
      if (lane < 2) {
        const int jw = it * 8 + w * 2 + lane;
        pkT[(size_t)jw * V + blk] = (unsigned int)(m >> (lane * 32));
      }
    }
  } else if (blk == V) {
    const int h = threadIdx.x;  // 0..255
    float sL = 0.f, sR = 0.f;
    for (int d = 0; d < D; ++d) {
      const float wv = W[(size_t)d * H + h];
      sL += wv * a[d];
      sR += wv * a[D + d];
    }
    vL[h] = sL;
    vR[h] = sR;
  } else {
    const int t = threadIdx.x;
    for (int i = 0; i < D; ++i)
      Wh[(size_t)i * H + t] = (_Float16)W[(size_t)i * H + t];
  }
}

// -------- K_proj: phase0 stage x->f16 LDS + e_i/e_j; phase1 f16 MFMA GEMM;
//          transpose via st; fragment store to pTf (R12, verified) --------
__global__ __launch_bounds__(256, 2) void k_proj(const float* __restrict__ x,
                                                 const _Float16* __restrict__ Wh,
                                                 const float* __restrict__ vL,
                                                 const float* __restrict__ vR,
                                                 _Float16* __restrict__ pTf,
                                                 float* __restrict__ ei,
                                                 _Float16* __restrict__ Fh,
                                                 _Float16* __restrict__ Ph) {
  __shared__ char xls[32 * 512];      // 16 KB: 32 j-rows x 256 h f16, XOR-swizzled
  __shared__ _Float16 st[128][52];    // 13 KB transpose staging
  const int t = threadIdx.x, lane = t & 63, wave = t >> 6;
  const int b = blockIdx.x >> 6;
  const int jt0 = blockIdx.x & 63;
  const int j0 = jt0 * 32;
  const int kq = lane >> 4, l15 = lane & 15;

  // ---- phase 0: stage 8 rows per wave; fp32 e-dots fused ----
  {
    const float4 vl4 = *(const float4*)(vL + lane * 4);
    const float4 vr4 = *(const float4*)(vR + lane * 4);
#pragma unroll
    for (int rr = 0; rr < 8; ++rr) {
      const int row = wave * 8 + rr;
      const float4 xv = *(const float4*)(x + ((size_t)(b * V + j0 + row)) * H + lane * 4);
      uint32 u0 = pk2(xv.x, xv.y), u1 = pk2(xv.z, xv.w);
      const int off = row * 512 + ((lane * 8) ^ ((row & 7) << 4));
      *(uint32*)(xls + off) = u0;
      *(uint32*)(xls + off + 4) = u1;
      float eL = xv.x * vl4.x + xv.y * vl4.y + xv.z * vl4.z + xv.w * vl4.w;
      float eR = xv.x * vr4.x + xv.y * vr4.y + xv.z * vr4.z + xv.w * vr4.w;
#pragma unroll
      for (int off_ = 1; off_ < 64; off_ <<= 1) {
        eL += __shfl_xor(eL, off_, 64);
        eR += __shfl_xor(eR, off_, 64);
      }
      if (lane == 0) {
        const size_t r_ = (size_t)b * V + j0 + row;
        ei[r_] = eL;
        Fh[r_] = (_Float16)__expf(eR);
        Ph[r_] = (_Float16)__expf(0.2f * eR);
      }
    }
  }
  __syncthreads();

  // ---- phase 1: GEMM. wave owns d rows [wave*32, wave*32+32) ----
  f32x4 acc[2][2];  // [t_(dt pair)][jt]
#pragma unroll
  for (int i_ = 0; i_ < 2; ++i_)
#pragma unroll
    for (int j_ = 0; j_ < 2; ++j_) acc[i_][j_] = (f32x4){0.f, 0.f, 0.f, 0.f};

  const char* wbase = (const char*)Wh + ((size_t)(wave * 32 + l15) * H + kq * 8) * 2;
#pragma unroll
  for (int ks = 0; ks < 8; ++ks) {
    f16x8 aw[2], bx[2];
#pragma unroll
    for (int t_ = 0; t_ < 2; ++t_)
      aw[t_] = *(const f16x8*)(wbase + (t_ * 16 * H + ks * 32) * 2);
#pragma unroll
    for (int jt = 0; jt < 2; ++jt) {
      const int row = jt * 16 + l15;
      bx[jt] = *(const f16x8*)(xls + row * 512 + ((ks * 64 + kq * 16) ^ ((l15 & 7) << 4)));
    }
#pragma unroll
    for (int t_ = 0; t_ < 2; ++t_)
#pragma unroll
      for (int jt = 0; jt < 2; ++jt)
        acc[t_][jt] = __builtin_amdgcn_mfma_f32_16x16x32_f16(aw[t_], bx[jt], acc[t_][jt], 0, 0, 0);
  }

  // C regs -> st[d][j]
#pragma unroll
  for (int t_ = 0; t_ < 2; ++t_)
#pragma unroll
    for (int jt = 0; jt < 2; ++jt)
#pragma unroll
      for (int r = 0; r < 4; ++r)
        st[(wave * 2 + t_) * 16 + kq * 4 + r][jt * 16 + l15] = (_Float16)acc[t_][jt][r];
  __syncthreads();

  // fragment store: pTf[b][c][dt][ks][lane][16B]
  const int c = jt0 >> 1;
  const int ksh = jt0 & 1;
  const int g = t >> 6;
#pragma unroll
  for (int ff = 0; ff < 2; ++ff) {
    const int dt = ff * 4 + g;
    const int dR = dt * 16 + l15;
    const int jc = kq * 8;
    union { unsigned long long ll[2]; f16x8 v; } vv_;
    vv_.ll[0] = *(const unsigned long long*)&st[dR][jc];
    vv_.ll[1] = *(const unsigned long long*)&st[dR][jc + 4];
    *(f16x8*)((char*)pTf +
              (((((size_t)b * 32 + c) * 8 + dt) * 2 + ksh) * 64 + lane) * 16) = vv_.v;
  }
}

// -------- K_attn: R11 geometry (wave = 32i x 32d), register-only mask gen --------
// bit->f16(2.0) via shift/AND into bit14/bit30; 0.5 compensation folded into Ei2/Eip2.
// No LDS, no barriers, chain-split accumulators, ones-column rowsum MFMA.

typedef union { uint4 v; uint32 u[4]; } U4;
typedef union { uint32 u[4]; f16x8 v; } AFu;
struct PFS {
  U4 FH0, FH1, PH0, PH1;  // F/P tables, shared by both i-groups
  uint32 w[2][2];         // adj words [ig][ks]
  AFu AF[2][2];           // A fragments [ig][ks]
};

#define PKMUL(d, a, b) asm("v_pk_mul_f16 %0, %1, %2" : "=v"(d) : "v"(a), "v"(b));
#define PKMAX(d, a, b) asm("v_pk_max_f16 %0, %1, %2" : "=v"(d) : "v"(a), "v"(b));

#define WGEN(S)                                                        \
  _Pragma("unroll") for (int ig_ = 0; ig_ < 2; ++ig_) {                \
    const uint32 E2_ = Ei2g[ig_], EP2_ = Eip2g[ig_];                   \
    _Pragma("unroll") for (int ks_ = 0; ks_ < 2; ++ks_) {              \
      const uint32 sh_ = (S).w[ig_][ks_] >> kq8;                       \
      _Pragma("unroll") for (int p_ = 0; p_ < 4; ++p_) {               \
        uint32 t0_, t1_;                                               \
        PKMUL(t0_, E2_, (ks_ ? (S).FH1 : (S).FH0).u[p_])               \
        PKMUL(t1_, EP2_, (ks_ ? (S).PH1 : (S).PH0).u[p_])              \
        PKMAX(t0_, t0_, t1_)                                           \
        const uint32 m_ = ((sh_ << (14 - 2 * p_)) & 0x4000u) |         \
                          ((sh_ << (29 - 2 * p_)) & 0x40000000u);      \
        PKMUL((S).AF[ig_][ks_].u[p_], t0_, m_)                         \
      }                                                                \
    }                                                                  \
  }

#define PFETCH(S, C)                                       \
  {                                                        \
    const char* f_ = fbase + (C) * 128 + kq16;             \
    const char* p_ = pbase + (C) * 128 + kq16;             \
    (S).FH0.v = *(const uint4*)(f_);                       \
    (S).FH1.v = *(const uint4*)(f_ + 64);                  \
    (S).PH0.v = *(const uint4*)(p_);                       \
    (S).PH1.v = *(const uint4*)(p_ + 64);                  \
    (S).w[0][0] = adjpT[(size_t)((C) * 2) * V + iR0];      \
    (S).w[0][1] = adjpT[(size_t)((C) * 2 + 1) * V + iR0];  \
    (S).w[1][0] = adjpT[(size_t)((C) * 2) * V + iR1];      \
    (S).w[1][1] = adjpT[(size_t)((C) * 2 + 1) * V + iR1];  \
  }

#define LOADB(BR, C)                                      \
  {                                                       \
    const char* g_ = gbase + (size_t)(C) * 16384;         \
    _Pragma("unroll") for (int q_ = 0; q_ < 4; ++q_)      \
      BR[q_] = *(const f16x8*)(g_ + q_ * 1024);           \
  }

#define DOMFMA(S, BX)                                                          \
  _Pragma("unroll") for (int ig_ = 0; ig_ < 2; ++ig_)                          \
    _Pragma("unroll") for (int nt_ = 0; nt_ < 2; ++nt_)                        \
      _Pragma("unroll") for (int ks_ = 0; ks_ < 2; ++ks_)                      \
        acc[ig_][nt_][ks_] = __builtin_amdgcn_mfma_f32_16x16x32_f16(           \
            (S).AF[ig_][ks_].v, BX[nt_ * 2 + ks_], acc[ig_][nt_][ks_], 0, 0, 0); \
  _Pragma("unroll") for (int ig_ = 0; ig_ < 2; ++ig_)                          \
    _Pragma("unroll") for (int ks_ = 0; ks_ < 2; ++ks_)                        \
      accS[ig_][ks_] = __builtin_amdgcn_mfma_f32_16x16x32_f16(                 \
          (S).AF[ig_][ks_].v, onesv, accS[ig_][ks_], 0, 0, 0);

#define BODYF(C, SX, BX, SY)   \
  {                            \
    DOMFMA(SX, BX)             \
    WGEN(SY)                   \
    LOADB(BX, (C) + 2)         \
    PFETCH(SX, (C) + 2)        \
  }

__global__ __launch_bounds__(256, 2) void k_attn(
    const _Float16* __restrict__ pTf,
    const float* __restrict__ ei,
    const _Float16* __restrict__ Fht,
    const _Float16* __restrict__ Pht,
    const unsigned int* __restrict__ adjpT,
    float* __restrict__ out) {
  const int t = threadIdx.x, lane = t & 63, wave = t >> 6;
  const int ih = wave >> 1;  // i-half of block (0/1)
  const int dq = wave & 1;   // d-quarter of dh-half (0/1)
  // bijective XCD chunk swizzle (nwg=512, 64 per XCD)
  const int pay = (blockIdx.x & 7) * 64 + (blockIdx.x >> 3);
  const int bdh = pay >> 4;   // 0..31
  const int itl = pay & 15;
  const int b = bdh >> 2, dh = (bdh >> 1) & 1;
  const int it = ((bdh & 1) << 4) | itl;  // 0..31
  const int i0b = it * 64;
  const int kq = lane >> 4;
  const int kq8 = kq * 8;
  const int kq16 = kq * 16;
  const int l15 = lane & 15;
  const int ibase = i0b + ih * 32;
  const int iR0 = ibase + l15;
  const int iR1 = iR0 + 16;

  const float eiv0 = ei[(size_t)b * V + iR0];
  const float eiv1 = ei[(size_t)b * V + iR1];
  uint32 Ei2g[2], Eip2g[2];
  {
    // 0.5x folded in to compensate the f16 2.0-mask
    const float e0 = 0.5f * __expf(eiv0), e1 = 0.5f * __expf(eiv1);
    const float p0 = 0.5f * __expf(0.2f * eiv0), p1 = 0.5f * __expf(0.2f * eiv1);
    Ei2g[0] = pk2(e0, e0); Ei2g[1] = pk2(e1, e1);
    Eip2g[0] = pk2(p0, p0); Eip2g[1] = pk2(p1, p1);
  }
  const char* fbase = (const char*)(Fht + (size_t)b * V);
  const char* pbase = (const char*)(Pht + (size_t)b * V);
  const size_t fb0 = ((size_t)b * 32) * 16384 + (size_t)dh * 8192;
  const char* gbase = (const char*)pTf + fb0 + dq * 4096 + lane * 16;

  union { uint32 u[4]; f16x8 v; } ones_;
  ones_.u[0] = ones_.u[1] = ones_.u[2] = ones_.u[3] = 0x3C003C00u;
  const f16x8 onesv = ones_.v;

  f32x4 acc[2][2][2];  // [ig][nt][ks]
#pragma unroll
  for (int a_ = 0; a_ < 2; ++a_)
#pragma unroll
    for (int b_ = 0; b_ < 2; ++b_)
#pragma unroll
      for (int c_ = 0; c_ < 2; ++c_) acc[a_][b_][c_] = (f32x4){0.f, 0.f, 0.f, 0.f};
  f32x4 accS[2][2];  // [ig][ks]
#pragma unroll
  for (int a_ = 0; a_ < 2; ++a_)
#pragma unroll
    for (int c_ = 0; c_ < 2; ++c_) accS[a_][c_] = (f32x4){0.f, 0.f, 0.f, 0.f};

  f16x8 bA[4], bB[4];
  PFS sA, sB;

  // prologue
  LOADB(bA, 0)
  LOADB(bB, 1)
  PFETCH(sA, 0)
  PFETCH(sB, 1)
  WGEN(sA)

  for (int c2 = 0; c2 < 15; ++c2) {
    const int c = c2 * 2;
    BODYF(c, sA, bA, sB)
    BODYF(c + 1, sB, bB, sA)
  }
  // tail: chunk 30 (af for 31 built, no more loads), chunk 31
  {
    DOMFMA(sA, bA)
    WGEN(sB)
  }
  { DOMFMA(sB, bB) }

  // epilogue: rowsums in accS (ones-column MFMA), lane-aligned
  float* ob = out + ((size_t)b * V + ibase) * D + dh * 64 + dq * 32 + l15;
#pragma unroll
  for (int ig = 0; ig < 2; ++ig) {
#pragma unroll
    for (int r = 0; r < 4; ++r) {
      const float inv_ = 1.0f / (accS[ig][0][r] + accS[ig][1][r]);
#pragma unroll
      for (int nt = 0; nt < 2; ++nt) {
        const float v = (acc[ig][nt][0][r] + acc[ig][nt][1][r]) * inv_;
        ob[(size_t)(ig * 16 + kq * 4 + r) * D + nt * 16] = fmaxf(v, 0.f);
      }
    }
  }
}

extern "C" void kernel_launch(void* const* d_in, const int* in_sizes, int n_in,
                              void* d_out, int out_size, void* d_ws, size_t ws_size,
                              hipStream_t stream) {
  const float* x = (const float*)d_in[0];
  const int* adj = (const int*)d_in[1];
  const float* W = (const float*)d_in[2];
  const float* a = (const float*)d_in[3];
  float* out = (float*)d_out;

  char* ws = (char*)d_ws;
  _Float16* pTf = (_Float16*)ws;                                   // 4 MB
  float* ei = (float*)(ws + (4u << 20));                           // 64 KB
  _Float16* Fh = (_Float16*)(ws + (4u << 20) + 65536);             // 32 KB
  _Float16* Ph = (_Float16*)(ws + (4u << 20) + 98304);             // 32 KB
  unsigned int* adjpT = (unsigned int*)(ws + (4u << 20) + 131072); // 512 KB
  float* vL = (float*)(ws + (4u << 20) + 655360);                  // 1 KB
  float* vR = (float*)(ws + (4u << 20) + 656384);                  // 1 KB
  _Float16* Wh = (_Float16*)(ws + (4u << 20) + 657408);            // 64 KB

  k_pack<<<dim3(V + 2), dim3(256), 0, stream>>>(adj, W, a, adjpT, vL, vR, Wh);
  k_proj<<<dim3(BATCH * (V / 32)), dim3(256), 0, stream>>>(x, Wh, vL, vR, pTf, ei, Fh, Ph);
  k_attn<<<dim3(BATCH * 2 * (V / 64)), dim3(256), 0, stream>>>(pTf, ei, Fh, Ph, adjpT, out);
}